// Round 9
// baseline (125.525 us; speedup 1.0000x reference)
//
#include <hip/hip_runtime.h>
#include <hip/hip_bf16.h>
#include <cstdint>

typedef __attribute__((ext_vector_type(8))) __bf16 bf16x8;
typedef __attribute__((ext_vector_type(4))) float f32x4;
typedef __attribute__((ext_vector_type(16))) float f32x16;

#define DM 1024
#define NH 16
#define DH 64
#define S_LEN 2048
#define BATCH 2

__device__ __forceinline__ ushort f2bf(float f) {
  union { float f; uint32_t u; } v; v.f = f;
  uint32_t u = v.u;
  uint32_t r = (u + 0x7fffu + ((u >> 16) & 1u)) >> 16;
  return (ushort)r;
}
__device__ __forceinline__ float bf2f(ushort h) {
  union { uint32_t u; float f; } v; v.u = ((uint32_t)h) << 16;
  return v.f;
}

__device__ __forceinline__ void gload16(const void* g, void* l) {
  __builtin_amdgcn_global_load_lds(
      (const __attribute__((address_space(1))) unsigned*)g,
      (__attribute__((address_space(3))) unsigned*)l, 16, 0, 0);
}

__device__ __forceinline__ float tmax16(const f32x16& v) {
  float a = fmaxf(fmaxf(v[0], v[1]), fmaxf(v[2], v[3]));
  float b = fmaxf(fmaxf(v[4], v[5]), fmaxf(v[6], v[7]));
  float c = fmaxf(fmaxf(v[8], v[9]), fmaxf(v[10], v[11]));
  float d = fmaxf(fmaxf(v[12], v[13]), fmaxf(v[14], v[15]));
  return fmaxf(fmaxf(a, b), fmaxf(c, d));
}
__device__ __forceinline__ float tsum16(const f32x16& v) {
  float a = (v[0] + v[1]) + (v[2] + v[3]);
  float b = (v[4] + v[5]) + (v[6] + v[7]);
  float c = (v[8] + v[9]) + (v[10] + v[11]);
  float d = (v[12] + v[13]) + (v[14] + v[15]);
  return (a + b) + (c + d);
}

// ---------------- prep: all f32->bf16 casts + rope table in one kernel ----------------
__global__ void prep(const float* __restrict__ x, const float* __restrict__ wqkv,
                     const float* __restrict__ wout,
                     ushort* __restrict__ xb, ushort* __restrict__ wqkvb,
                     ushort* __restrict__ woutb, float2* __restrict__ tab) {
  const int NX = 1048576, NW = 786432, NO = 262144, NT = 65536;
  for (int i = blockIdx.x * blockDim.x + threadIdx.x; i < NX + NW + NO + NT;
       i += gridDim.x * blockDim.x) {
    if (i < NX + NW + NO) {
      const float* src; ushort* dst; int j;
      if (i < NX)           { src = x;    dst = xb;    j = i; }
      else if (i < NX + NW) { src = wqkv; dst = wqkvb; j = i - NX; }
      else                  { src = wout; dst = woutb; j = i - NX - NW; }
      float4 v = ((const float4*)src)[j];
      ushort4 o;
      o.x = f2bf(v.x); o.y = f2bf(v.y); o.z = f2bf(v.z); o.w = f2bf(v.w);
      ((ushort4*)dst)[j] = o;
    } else {
      int j = i - NX - NW - NO;
      int fi = j & 31, s = j >> 5;
      float inv = expf(-(float)fi * (9.210340371976184f / 32.0f));
      float ang = (float)s * inv;
      float sn, cs;
      sincosf(ang, &sn, &cs);
      tab[j] = make_float2(cs, sn);
    }
  }
}

// ---------------- GEMM v4: m97 single-buffer + both-sides XOR swizzle (unchanged) ----------------
template<int WRITE_BF16>
__global__ __launch_bounds__(256) void gemm_bt4(
    const ushort* __restrict__ A, const ushort* __restrict__ B,
    void* __restrict__ Cv, int M, int N, int K)
{
  __shared__ ushort As[128][64];
  __shared__ ushort Bs[128][64];
  const int t = threadIdx.x;
  const int w = t >> 6, lane = t & 63;
  const int wm = w >> 1, wn = w & 1;
  const int lr = lane & 15, lk = lane >> 4;
  const int m0 = blockIdx.y * 128, n0 = blockIdx.x * 128;

  const int srow8 = lane >> 3;
  const int scol  = ((lane & 7) ^ srow8) * 8;

  f32x4 acc[4][4];
#pragma unroll
  for (int m = 0; m < 4; m++)
#pragma unroll
    for (int n = 0; n < 4; n++) acc[m][n] = (f32x4)(0.0f);

  for (int k0 = 0; k0 < K; k0 += 64) {
#pragma unroll
    for (int j = 0; j < 4; ++j) {
      const int c = w * 4 + j;
      const int row = c * 8 + srow8;
      gload16(&A[(size_t)(m0 + row) * K + k0 + scol], &As[c * 8][0]);
      gload16(&B[(size_t)(n0 + row) * K + k0 + scol], &Bs[c * 8][0]);
    }
    __syncthreads();

    bf16x8 af[4][2], bfr[4][2];
#pragma unroll
    for (int m = 0; m < 4; m++)
#pragma unroll
      for (int kk = 0; kk < 2; kk++) {
        const int ch = (((kk << 2) + lk) ^ (lr & 7)) * 8;
        af[m][kk] = *(const bf16x8*)&As[wm * 64 + m * 16 + lr][ch];
      }
#pragma unroll
    for (int n = 0; n < 4; n++)
#pragma unroll
      for (int kk = 0; kk < 2; kk++) {
        const int ch = (((kk << 2) + lk) ^ (lr & 7)) * 8;
        bfr[n][kk] = *(const bf16x8*)&Bs[wn * 64 + n * 16 + lr][ch];
      }

    __builtin_amdgcn_s_setprio(1);
#pragma unroll
    for (int kk = 0; kk < 2; kk++)
#pragma unroll
      for (int m = 0; m < 4; m++)
#pragma unroll
        for (int n = 0; n < 4; n++)
          acc[m][n] = __builtin_amdgcn_mfma_f32_16x16x32_bf16(af[m][kk], bfr[n][kk], acc[m][n], 0, 0, 0);
    __builtin_amdgcn_s_setprio(0);

    __syncthreads();
  }

#pragma unroll
  for (int m = 0; m < 4; m++) {
    int row = m0 + wm * 64 + m * 16 + lk * 4;
#pragma unroll
    for (int n = 0; n < 4; n++) {
      int col = n0 + wn * 64 + n * 16 + lr;
#pragma unroll
      for (int r = 0; r < 4; r++) {
        float val = acc[m][n][r];
        if (WRITE_BF16) ((ushort*)Cv)[(size_t)(row + r) * N + col] = f2bf(val);
        else            ((float*)Cv)[(size_t)(row + r) * N + col] = val;
      }
    }
  }
}

// ---------------- RoPE on q,k + repack to (BH, S, 64), vectorized ----------------
__global__ void rope_qk2(const ushort* __restrict__ qkv, const float2* __restrict__ tab,
                         ushort* __restrict__ Qh, ushort* __restrict__ Kh) {
  int idx = blockIdx.x * 256 + threadIdx.x;
  int i4 = idx & 7;
  int h  = (idx >> 3) & 15;
  int s  = (idx >> 7) & 2047;
  int b  = idx >> 18;
  const size_t base = ((size_t)(b * S_LEN + s)) * 3072 + h * 64 + i4 * 8;
  uint4 qv = *(const uint4*)&qkv[base];
  uint4 kv = *(const uint4*)&qkv[base + 1024];
  const float scale = 0.125f * 1.4426950408889634f;
  uint32_t qo[4], ko[4];
  const uint32_t* qw = (const uint32_t*)&qv;
  const uint32_t* kw = (const uint32_t*)&kv;
#pragma unroll
  for (int j = 0; j < 4; ++j) {
    float2 t2 = tab[s * 32 + i4 * 4 + j];
    float qr = bf2f((ushort)(qw[j] & 0xffff)), qi = bf2f((ushort)(qw[j] >> 16));
    float kr = bf2f((ushort)(kw[j] & 0xffff)), ki = bf2f((ushort)(kw[j] >> 16));
    float oqr = (qr * t2.x - qi * t2.y) * scale, oqi = (qr * t2.y + qi * t2.x) * scale;
    float okr = kr * t2.x - ki * t2.y,           oki = kr * t2.y + ki * t2.x;
    qo[j] = (uint32_t)f2bf(oqr) | ((uint32_t)f2bf(oqi) << 16);
    ko[j] = (uint32_t)f2bf(okr) | ((uint32_t)f2bf(oki) << 16);
  }
  const size_t ob = ((size_t)((b * NH + h) * S_LEN + s)) * 64 + i4 * 8;
  *(uint4*)&Qh[ob] = *(const uint4*)qo;
  *(uint4*)&Kh[ob] = *(const uint4*)ko;
}

// ---------------- V: (b,s,h,d) slice of qkv -> Vt (BH, 64, S) ----------------
__global__ __launch_bounds__(256) void transpose_v(const ushort* __restrict__ qkv, ushort* __restrict__ Vt) {
  __shared__ ushort tile[64][72];
  int st = blockIdx.x;
  int bh = blockIdx.y;
  int b = bh >> 4, h = bh & 15;
  int t = threadIdx.x;
#pragma unroll
  for (int p = 0; p < 2; p++) {
    int c = t + p * 256;
    int srow = c >> 3;
    int d8 = (c & 7) * 8;
    *(uint4*)&tile[srow][d8] =
        *(const uint4*)&qkv[((size_t)(b * S_LEN + st * 64 + srow)) * 3072 + 2048 + h * 64 + d8];
  }
  __syncthreads();
#pragma unroll
  for (int p = 0; p < 2; p++) {
    int c = t + p * 256;
    int d = c >> 3;
    int s8 = (c & 7) * 8;
    ushort tmp[8];
#pragma unroll
    for (int j = 0; j < 8; j++) tmp[j] = tile[s8 + j][d];
    *(uint4*)&Vt[((size_t)(bh * 64 + d)) * S_LEN + st * 64 + s8] = *(uint4*)tmp;
  }
}

// ---------------- causal flash attention v6: split-KV ----------------
// Grid (bh=32, y=16, half=2). qt = 15-y (heavy first). Each (bh,qt) is computed
// by two equal-work blocks: half0 k-tiles [0,qt+1), half1 [qt+1,2qt+2).
// Partials: normalized O-hat (bf16) + per-row (m,l), merged by attn_combine.
// Body identical to v5 (4 waves, 128 q-rows, KVBLK=64 dbuf, T12/T13).
union SMemU {
  struct { ushort K[2][64][64]; ushort V[2][64][64]; } kv;  // 32 KB
  ushort Ot[128][68];
};

__global__ __launch_bounds__(256) void flash_attn6(
    const ushort* __restrict__ Qh, const ushort* __restrict__ Kh, const ushort* __restrict__ Vt,
    ushort* __restrict__ op, float2* __restrict__ ml)
{
  __shared__ __align__(16) SMemU sm;

  const int bh = blockIdx.x;               // XCD = bh % 8
  const int qt = 15 - blockIdx.y;          // heavy first
  const int half = blockIdx.z;
  const int t = threadIdx.x;
  const int w = t >> 6, lane = t & 63;
  const int q5 = lane & 31, hi = lane >> 5;

  const int qbase_w = qt * 128 + w * 32;
  const int qg = qbase_w + q5;

  bf16x8 qreg[4];
  {
    const size_t qb = ((size_t)bh * S_LEN + qg) * 64;
#pragma unroll
    for (int c = 0; c < 4; ++c)
      qreg[c] = *(const bf16x8*)&Qh[qb + c * 16 + hi * 8];
  }

  f32x16 oacc[2];
  oacc[0] = (f32x16)(0.0f); oacc[1] = (f32x16)(0.0f);
  float mrun = -1e30f, lsum = 0.0f;

  const ushort* Kg = &Kh[((size_t)bh * S_LEN) * 64];
  const ushort* Vg = &Vt[((size_t)bh * 64) * S_LEN];

  auto STAGE = [&](int bf, int jt) {
#pragma unroll
    for (int p = 0; p < 2; ++p) {
      const int row = w * 16 + p * 8 + (lane >> 3);
      const int c16 = (lane & 7) ^ (row & 7);
      gload16(&Kg[((size_t)(jt * 64 + row)) * 64 + c16 * 8], &sm.kv.K[bf][w * 16 + p * 8][0]);
      gload16(&Vg[((size_t)row) * S_LEN + jt * 64 + c16 * 8], &sm.kv.V[bf][w * 16 + p * 8][0]);
    }
  };

  const int j0 = half ? (qt + 1) : 0;
  const int j1 = half ? (2 * qt + 2) : (qt + 1);

  STAGE(0, j0);
  __syncthreads();

  int cur = 0;
  for (int jt = j0; jt < j1; ++jt) {
    if (jt + 1 < j1) STAGE(cur ^ 1, jt + 1);

    const bool active = (jt * 64 <= qbase_w + 31);   // wave-uniform
    if (active) {
      f32x16 sc[2];
      sc[0] = (f32x16)(0.0f); sc[1] = (f32x16)(0.0f);
      __builtin_amdgcn_s_setprio(1);
#pragma unroll
      for (int kg = 0; kg < 2; ++kg) {
        const int kr = kg * 32 + q5;
#pragma unroll
        for (int c = 0; c < 4; ++c) {
          bf16x8 kf = *(const bf16x8*)&sm.kv.K[cur][kr][((c * 2 + hi) ^ (kr & 7)) * 8];
          sc[kg] = __builtin_amdgcn_mfma_f32_32x32x16_bf16(kf, qreg[c], sc[kg], 0, 0, 0);
        }
      }
      __builtin_amdgcn_s_setprio(0);

      if (jt * 64 + 63 > qbase_w) {
        const int kb = jt * 64;
#pragma unroll
        for (int r = 0; r < 16; ++r) {
          const int kl = kb + (r & 3) + 8 * (r >> 2) + 4 * hi;
          if (kl > qg)      sc[0][r] = -1e30f;
          if (kl + 32 > qg) sc[1][r] = -1e30f;
        }
      }

      float pmax = fmaxf(tmax16(sc[0]), tmax16(sc[1]));
      pmax = fmaxf(pmax, __shfl_xor(pmax, 32, 64));
      if (!__all(pmax - mrun <= 8.0f)) {
        const float mnew = fmaxf(mrun, pmax);
        const float alpha = __builtin_amdgcn_exp2f(mrun - mnew);
        mrun = mnew;
        lsum *= alpha;
#pragma unroll
        for (int r = 0; r < 16; ++r) { oacc[0][r] *= alpha; oacc[1][r] *= alpha; }
      }
#pragma unroll
      for (int kg = 0; kg < 2; ++kg)
#pragma unroll
        for (int r = 0; r < 16; ++r)
          sc[kg][r] = __builtin_amdgcn_exp2f(sc[kg][r] - mrun);
      float rsum = tsum16(sc[0]) + tsum16(sc[1]);
      rsum += __shfl_xor(rsum, 32, 64);
      lsum += rsum;

      bf16x8 pf[4];
#pragma unroll
      for (int kc = 0; kc < 4; ++kc) {
        const int kg = kc >> 1, rA = (kc & 1) * 8, rB = rA + 4;
        uint32_t A0, A1, B0, B1;
        asm("v_cvt_pk_bf16_f32 %0, %1, %2" : "=v"(A0) : "v"(sc[kg][rA + 0]), "v"(sc[kg][rA + 1]));
        asm("v_cvt_pk_bf16_f32 %0, %1, %2" : "=v"(A1) : "v"(sc[kg][rA + 2]), "v"(sc[kg][rA + 3]));
        asm("v_cvt_pk_bf16_f32 %0, %1, %2" : "=v"(B0) : "v"(sc[kg][rB + 0]), "v"(sc[kg][rB + 1]));
        asm("v_cvt_pk_bf16_f32 %0, %1, %2" : "=v"(B1) : "v"(sc[kg][rB + 2]), "v"(sc[kg][rB + 3]));
        asm("v_permlane32_swap_b32 %0, %1" : "+v"(A0), "+v"(B0));
        asm("v_permlane32_swap_b32 %0, %1" : "+v"(A1), "+v"(B1));
        union { uint32_t u[4]; bf16x8 v; } cv;
        cv.u[0] = A0; cv.u[1] = A1; cv.u[2] = B0; cv.u[3] = B1;
        pf[kc] = cv.v;
      }

      __builtin_amdgcn_s_setprio(1);
#pragma unroll
      for (int dg = 0; dg < 2; ++dg) {
        const int vr = dg * 32 + q5;
#pragma unroll
        for (int kc = 0; kc < 4; ++kc) {
          bf16x8 vf = *(const bf16x8*)&sm.kv.V[cur][vr][((kc * 2 + hi) ^ (vr & 7)) * 8];
          oacc[dg] = __builtin_amdgcn_mfma_f32_32x32x16_bf16(vf, pf[kc], oacc[dg], 0, 0, 0);
        }
      }
      __builtin_amdgcn_s_setprio(0);
    }

    __syncthreads();
    cur ^= 1;
  }

  // ---- epilogue: per-row (m,l) + normalized O-hat (bf16) partials ----
  if (hi == 0)
    ml[(size_t)(half * 32 + bh) * S_LEN + qg] = make_float2(mrun, lsum);

  const float inv = (lsum > 0.0f) ? (1.0f / lsum) : 0.0f;
#pragma unroll
  for (int dg = 0; dg < 2; ++dg)
#pragma unroll
    for (int g = 0; g < 4; ++g) {
      ushort4 ok;
      ok.x = f2bf(oacc[dg][4 * g + 0] * inv); ok.y = f2bf(oacc[dg][4 * g + 1] * inv);
      ok.z = f2bf(oacc[dg][4 * g + 2] * inv); ok.w = f2bf(oacc[dg][4 * g + 3] * inv);
      *(ushort4*)&sm.Ot[w * 32 + q5][dg * 32 + g * 8 + 4 * hi] = ok;
    }
  __syncthreads();
  {
    const int row = t >> 1, c32 = (t & 1) * 32;
    const size_t gb = ((size_t)(half * 32 + bh) * S_LEN + qt * 128 + row) * 64 + c32;
#pragma unroll
    for (int j = 0; j < 4; ++j)
      *(uint4*)&op[gb + j * 8] = *(const uint4*)&sm.Ot[row][c32 + j * 8];
  }
}

// ---------------- combine the two split-KV halves ----------------
__global__ void attn_combine(const ushort* __restrict__ op, const float2* __restrict__ ml,
                             ushort* __restrict__ Ob) {
  const int idx = blockIdx.x * 256 + threadIdx.x;   // 524288 = 65536 rows x 8
  const int d8 = (idx & 7) * 8;
  const int row = idx >> 3;                          // bh*2048 + q
  const int bh = row >> 11, q = row & 2047;
  const int b = bh >> 4, h = bh & 15;

  const float2 m1 = ml[row];
  const float2 m2 = ml[65536 + row];
  const float m = fmaxf(m1.x, m2.x);
  const float w1 = m1.y * __builtin_amdgcn_exp2f(m1.x - m);
  const float w2 = m2.y * __builtin_amdgcn_exp2f(m2.x - m);
  const float s = 1.0f / (w1 + w2);
  const float s1 = w1 * s, s2 = w2 * s;

  uint4 a = *(const uint4*)&op[(size_t)row * 64 + d8];
  uint4 c = *(const uint4*)&op[(size_t)(65536 + row) * 64 + d8];
  const uint32_t* aw = (const uint32_t*)&a;
  const uint32_t* cw = (const uint32_t*)&c;
  uint32_t o[4];
#pragma unroll
  for (int j = 0; j < 4; ++j) {
    float lo = s1 * bf2f((ushort)(aw[j] & 0xffff)) + s2 * bf2f((ushort)(cw[j] & 0xffff));
    float hi = s1 * bf2f((ushort)(aw[j] >> 16))    + s2 * bf2f((ushort)(cw[j] >> 16));
    o[j] = (uint32_t)f2bf(lo) | ((uint32_t)f2bf(hi) << 16);
  }
  *(uint4*)&Ob[((size_t)(b * S_LEN + q)) * DM + h * 64 + d8] = *(const uint4*)o;
}

extern "C" void kernel_launch(void* const* d_in, const int* in_sizes, int n_in,
                              void* d_out, int out_size, void* d_ws, size_t ws_size,
                              hipStream_t stream) {
  const float* x     = (const float*)d_in[0];
  const float* w_qkv = (const float*)d_in[2];
  const float* w_out = (const float*)d_in[3];
  float* out = (float*)d_out;

  char* ws = (char*)d_ws;
  ushort* xb    = (ushort*)(ws);
  ushort* wqkvb = (ushort*)(ws + 8388608);
  ushort* woutb = (ushort*)(ws + 14680064);
  ushort* qkvb  = (ushort*)(ws + 16777216);   // 24 MB; dead after rope+transpose
  ushort* Qh    = (ushort*)(ws + 41943040);
  ushort* Kh    = (ushort*)(ws + 50331648);
  ushort* Vt    = (ushort*)(ws + 58720256);
  ushort* Ob    = (ushort*)(ws + 67108864);
  float2* tab   = (float2*)(ws + 75497472);
  // split-KV partials reuse the dead qkvb region:
  ushort* op    = (ushort*)(ws + 16777216);   // 16 MB: (2,32,2048,64) bf16
  float2* ml    = (float2*)(ws + 33554432);   //  1 MB: (2,32,2048) float2

  prep<<<2048, 256, 0, stream>>>(x, w_qkv, w_out, xb, wqkvb, woutb, tab);

  gemm_bt4<1><<<dim3(24, 32), 256, 0, stream>>>(xb, wqkvb, qkvb, 4096, 3072, 1024);

  rope_qk2<<<2048, 256, 0, stream>>>(qkvb, tab, Qh, Kh);
  transpose_v<<<dim3(32, 32), 256, 0, stream>>>(qkvb, Vt);

  flash_attn6<<<dim3(32, 16, 2), 256, 0, stream>>>(Qh, Kh, Vt, op, ml);
  attn_combine<<<2048, 256, 0, stream>>>(op, ml, Ob);

  gemm_bt4<0><<<dim3(8, 32), 256, 0, stream>>>(Ob, woutb, out, 4096, 1024, 1024);
}

// Round 10
// 122.988 us; speedup vs baseline: 1.0206x; 1.0206x over previous
//
#include <hip/hip_runtime.h>
#include <hip/hip_bf16.h>
#include <cstdint>

typedef __attribute__((ext_vector_type(8))) __bf16 bf16x8;
typedef __attribute__((ext_vector_type(4))) float f32x4;
typedef __attribute__((ext_vector_type(16))) float f32x16;

#define DM 1024
#define NH 16
#define DH 64
#define S_LEN 2048
#define BATCH 2

__device__ __forceinline__ ushort f2bf(float f) {
  union { float f; uint32_t u; } v; v.f = f;
  uint32_t u = v.u;
  uint32_t r = (u + 0x7fffu + ((u >> 16) & 1u)) >> 16;
  return (ushort)r;
}
__device__ __forceinline__ float bf2f(ushort h) {
  union { uint32_t u; float f; } v; v.u = ((uint32_t)h) << 16;
  return v.f;
}

__device__ __forceinline__ void gload16(const void* g, void* l) {
  __builtin_amdgcn_global_load_lds(
      (const __attribute__((address_space(1))) unsigned*)g,
      (__attribute__((address_space(3))) unsigned*)l, 16, 0, 0);
}

__device__ __forceinline__ float tmax16(const f32x16& v) {
  float a = fmaxf(fmaxf(v[0], v[1]), fmaxf(v[2], v[3]));
  float b = fmaxf(fmaxf(v[4], v[5]), fmaxf(v[6], v[7]));
  float c = fmaxf(fmaxf(v[8], v[9]), fmaxf(v[10], v[11]));
  float d = fmaxf(fmaxf(v[12], v[13]), fmaxf(v[14], v[15]));
  return fmaxf(fmaxf(a, b), fmaxf(c, d));
}
__device__ __forceinline__ float tsum16(const f32x16& v) {
  float a = (v[0] + v[1]) + (v[2] + v[3]);
  float b = (v[4] + v[5]) + (v[6] + v[7]);
  float c = (v[8] + v[9]) + (v[10] + v[11]);
  float d = (v[12] + v[13]) + (v[14] + v[15]);
  return (a + b) + (c + d);
}

// ---------------- prep: all f32->bf16 casts + rope table in one kernel ----------------
__global__ void prep(const float* __restrict__ x, const float* __restrict__ wqkv,
                     const float* __restrict__ wout,
                     ushort* __restrict__ xb, ushort* __restrict__ wqkvb,
                     ushort* __restrict__ woutb, float2* __restrict__ tab) {
  const int NX = 1048576, NW = 786432, NO = 262144, NT = 65536;
  for (int i = blockIdx.x * blockDim.x + threadIdx.x; i < NX + NW + NO + NT;
       i += gridDim.x * blockDim.x) {
    if (i < NX + NW + NO) {
      const float* src; ushort* dst; int j;
      if (i < NX)           { src = x;    dst = xb;    j = i; }
      else if (i < NX + NW) { src = wqkv; dst = wqkvb; j = i - NX; }
      else                  { src = wout; dst = woutb; j = i - NX - NW; }
      float4 v = ((const float4*)src)[j];
      ushort4 o;
      o.x = f2bf(v.x); o.y = f2bf(v.y); o.z = f2bf(v.z); o.w = f2bf(v.w);
      ((ushort4*)dst)[j] = o;
    } else {
      int j = i - NX - NW - NO;
      int fi = j & 31, s = j >> 5;
      float inv = expf(-(float)fi * (9.210340371976184f / 32.0f));
      float ang = (float)s * inv;
      float sn, cs;
      sincosf(ang, &sn, &cs);
      tab[j] = make_float2(cs, sn);
    }
  }
}

// ---------------- fused QKV GEMM: gemm_bt4 body + rope/transpose epilogue ----------------
// C = x @ w_qkv^T (4096 x 3072, K=1024). Each 128-col tile lies in one region:
// blockIdx.x 0-7 -> Q (rope + scale -> Qh), 8-15 -> K (rope -> Kh),
// 16-23 -> V (LDS transpose -> Vt). Rope pairs are adjacent lanes: shfl_xor(1).
__global__ __launch_bounds__(256) void gemm_qkv(
    const ushort* __restrict__ A, const ushort* __restrict__ B,
    const float2* __restrict__ tab,
    ushort* __restrict__ Qh, ushort* __restrict__ Kh, ushort* __restrict__ Vt)
{
  union SM {
    struct { ushort As[128][64]; ushort Bs[128][64]; } s;  // 32 KB staging
    ushort vt[128][130];                                   // V-epilogue alias
  };
  __shared__ __align__(16) SM sm;

  const int K = 1024;
  const int t = threadIdx.x;
  const int w = t >> 6, lane = t & 63;
  const int wm = w >> 1, wn = w & 1;
  const int lr = lane & 15, lk = lane >> 4;
  const int m0 = blockIdx.y * 128, n0 = blockIdx.x * 128;

  const int srow8 = lane >> 3;
  const int scol  = ((lane & 7) ^ srow8) * 8;

  f32x4 acc[4][4];
#pragma unroll
  for (int m = 0; m < 4; m++)
#pragma unroll
    for (int n = 0; n < 4; n++) acc[m][n] = (f32x4)(0.0f);

  for (int k0 = 0; k0 < K; k0 += 64) {
#pragma unroll
    for (int j = 0; j < 4; ++j) {
      const int c = w * 4 + j;
      const int row = c * 8 + srow8;
      gload16(&A[(size_t)(m0 + row) * K + k0 + scol], &sm.s.As[c * 8][0]);
      gload16(&B[(size_t)(n0 + row) * K + k0 + scol], &sm.s.Bs[c * 8][0]);
    }
    __syncthreads();

    bf16x8 af[4][2], bfr[4][2];
#pragma unroll
    for (int m = 0; m < 4; m++)
#pragma unroll
      for (int kk = 0; kk < 2; kk++) {
        const int ch = (((kk << 2) + lk) ^ (lr & 7)) * 8;
        af[m][kk] = *(const bf16x8*)&sm.s.As[wm * 64 + m * 16 + lr][ch];
      }
#pragma unroll
    for (int n = 0; n < 4; n++)
#pragma unroll
      for (int kk = 0; kk < 2; kk++) {
        const int ch = (((kk << 2) + lk) ^ (lr & 7)) * 8;
        bfr[n][kk] = *(const bf16x8*)&sm.s.Bs[wn * 64 + n * 16 + lr][ch];
      }

    __builtin_amdgcn_s_setprio(1);
#pragma unroll
    for (int kk = 0; kk < 2; kk++)
#pragma unroll
      for (int m = 0; m < 4; m++)
#pragma unroll
        for (int n = 0; n < 4; n++)
          acc[m][n] = __builtin_amdgcn_mfma_f32_16x16x32_bf16(af[m][kk], bfr[n][kk], acc[m][n], 0, 0, 0);
    __builtin_amdgcn_s_setprio(0);

    __syncthreads();
  }

  const int reg  = n0 >> 10;       // 0=Q, 1=K, 2=V
  const int cb   = n0 & 1023;      // col offset within region
  const int b    = m0 >> 11;
  const int s0   = m0 & 2047;

  if (reg < 2) {
    ushort* dst = reg ? Kh : Qh;
    const float qs = reg ? 1.0f : 0.125f * 1.4426950408889634f;
    const float pm = (lr & 1) ? 1.0f : -1.0f;   // sgn on partner*sin
#pragma unroll
    for (int m = 0; m < 4; m++) {
      const int rowl = wm * 64 + m * 16 + lk * 4;
#pragma unroll
      for (int n = 0; n < 4; n++) {
        const int cq = cb + wn * 64 + n * 16 + lr;
        const int h = cq >> 6, d = cq & 63, i2 = (cq & 63) >> 1;
#pragma unroll
        for (int r = 0; r < 4; r++) {
          const int s = s0 + rowl + r;
          float x = acc[m][n][r];
          float p = __shfl_xor(x, 1, 64);
          float2 t2 = tab[s * 32 + i2];
          float o = (x * t2.x + pm * p * t2.y) * qs;
          dst[((size_t)((b * NH + h) * S_LEN + s)) * 64 + d] = f2bf(o);
        }
      }
    }
  } else {
    // V: tile -> LDS -> transposed coalesced store to Vt (BH, 64, S)
#pragma unroll
    for (int m = 0; m < 4; m++)
#pragma unroll
      for (int n = 0; n < 4; n++)
#pragma unroll
        for (int r = 0; r < 4; r++)
          sm.vt[wm * 64 + m * 16 + lk * 4 + r][wn * 64 + n * 16 + lr] = f2bf(acc[m][n][r]);
    __syncthreads();
    const int h0 = cb >> 6;
#pragma unroll
    for (int p = 0; p < 8; ++p) {
      const int tid = t + p * 256;
      const int cl = tid >> 4;           // 0..127 (2 heads x 64 d)
      const int s8 = (tid & 15) * 8;     // 0..120
      const int h = h0 + (cl >> 6), d = cl & 63;
      ushort tmp[8];
#pragma unroll
      for (int j = 0; j < 8; j++) tmp[j] = sm.vt[s8 + j][cl];
      *(uint4*)&Vt[((size_t)((b * NH + h) * 64 + d)) * S_LEN + s0 + s8] = *(const uint4*)tmp;
    }
  }
}

// ---------------- GEMM v4 (unchanged, used for out-proj) ----------------
template<int WRITE_BF16>
__global__ __launch_bounds__(256) void gemm_bt4(
    const ushort* __restrict__ A, const ushort* __restrict__ B,
    void* __restrict__ Cv, int M, int N, int K)
{
  __shared__ ushort As[128][64];
  __shared__ ushort Bs[128][64];
  const int t = threadIdx.x;
  const int w = t >> 6, lane = t & 63;
  const int wm = w >> 1, wn = w & 1;
  const int lr = lane & 15, lk = lane >> 4;
  const int m0 = blockIdx.y * 128, n0 = blockIdx.x * 128;

  const int srow8 = lane >> 3;
  const int scol  = ((lane & 7) ^ srow8) * 8;

  f32x4 acc[4][4];
#pragma unroll
  for (int m = 0; m < 4; m++)
#pragma unroll
    for (int n = 0; n < 4; n++) acc[m][n] = (f32x4)(0.0f);

  for (int k0 = 0; k0 < K; k0 += 64) {
#pragma unroll
    for (int j = 0; j < 4; ++j) {
      const int c = w * 4 + j;
      const int row = c * 8 + srow8;
      gload16(&A[(size_t)(m0 + row) * K + k0 + scol], &As[c * 8][0]);
      gload16(&B[(size_t)(n0 + row) * K + k0 + scol], &Bs[c * 8][0]);
    }
    __syncthreads();

    bf16x8 af[4][2], bfr[4][2];
#pragma unroll
    for (int m = 0; m < 4; m++)
#pragma unroll
      for (int kk = 0; kk < 2; kk++) {
        const int ch = (((kk << 2) + lk) ^ (lr & 7)) * 8;
        af[m][kk] = *(const bf16x8*)&As[wm * 64 + m * 16 + lr][ch];
      }
#pragma unroll
    for (int n = 0; n < 4; n++)
#pragma unroll
      for (int kk = 0; kk < 2; kk++) {
        const int ch = (((kk << 2) + lk) ^ (lr & 7)) * 8;
        bfr[n][kk] = *(const bf16x8*)&Bs[wn * 64 + n * 16 + lr][ch];
      }

    __builtin_amdgcn_s_setprio(1);
#pragma unroll
    for (int kk = 0; kk < 2; kk++)
#pragma unroll
      for (int m = 0; m < 4; m++)
#pragma unroll
        for (int n = 0; n < 4; n++)
          acc[m][n] = __builtin_amdgcn_mfma_f32_16x16x32_bf16(af[m][kk], bfr[n][kk], acc[m][n], 0, 0, 0);
    __builtin_amdgcn_s_setprio(0);

    __syncthreads();
  }

#pragma unroll
  for (int m = 0; m < 4; m++) {
    int row = m0 + wm * 64 + m * 16 + lk * 4;
#pragma unroll
    for (int n = 0; n < 4; n++) {
      int col = n0 + wn * 64 + n * 16 + lr;
#pragma unroll
      for (int r = 0; r < 4; r++) {
        float val = acc[m][n][r];
        if (WRITE_BF16) ((ushort*)Cv)[(size_t)(row + r) * N + col] = f2bf(val);
        else            ((float*)Cv)[(size_t)(row + r) * N + col] = val;
      }
    }
  }
}

// ---------------- causal flash attention v6: split-KV (unchanged) ----------------
union SMemU {
  struct { ushort K[2][64][64]; ushort V[2][64][64]; } kv;  // 32 KB
  ushort Ot[128][68];
};

__global__ __launch_bounds__(256) void flash_attn6(
    const ushort* __restrict__ Qh, const ushort* __restrict__ Kh, const ushort* __restrict__ Vt,
    ushort* __restrict__ op, float2* __restrict__ ml)
{
  __shared__ __align__(16) SMemU sm;

  const int bh = blockIdx.x;
  const int qt = 15 - blockIdx.y;
  const int half = blockIdx.z;
  const int t = threadIdx.x;
  const int w = t >> 6, lane = t & 63;
  const int q5 = lane & 31, hi = lane >> 5;

  const int qbase_w = qt * 128 + w * 32;
  const int qg = qbase_w + q5;

  bf16x8 qreg[4];
  {
    const size_t qb = ((size_t)bh * S_LEN + qg) * 64;
#pragma unroll
    for (int c = 0; c < 4; ++c)
      qreg[c] = *(const bf16x8*)&Qh[qb + c * 16 + hi * 8];
  }

  f32x16 oacc[2];
  oacc[0] = (f32x16)(0.0f); oacc[1] = (f32x16)(0.0f);
  float mrun = -1e30f, lsum = 0.0f;

  const ushort* Kg = &Kh[((size_t)bh * S_LEN) * 64];
  const ushort* Vg = &Vt[((size_t)bh * 64) * S_LEN];

  auto STAGE = [&](int bf, int jt) {
#pragma unroll
    for (int p = 0; p < 2; ++p) {
      const int row = w * 16 + p * 8 + (lane >> 3);
      const int c16 = (lane & 7) ^ (row & 7);
      gload16(&Kg[((size_t)(jt * 64 + row)) * 64 + c16 * 8], &sm.kv.K[bf][w * 16 + p * 8][0]);
      gload16(&Vg[((size_t)row) * S_LEN + jt * 64 + c16 * 8], &sm.kv.V[bf][w * 16 + p * 8][0]);
    }
  };

  const int j0 = half ? (qt + 1) : 0;
  const int j1 = half ? (2 * qt + 2) : (qt + 1);

  STAGE(0, j0);
  __syncthreads();

  int cur = 0;
  for (int jt = j0; jt < j1; ++jt) {
    if (jt + 1 < j1) STAGE(cur ^ 1, jt + 1);

    const bool active = (jt * 64 <= qbase_w + 31);
    if (active) {
      f32x16 sc[2];
      sc[0] = (f32x16)(0.0f); sc[1] = (f32x16)(0.0f);
      __builtin_amdgcn_s_setprio(1);
#pragma unroll
      for (int kg = 0; kg < 2; ++kg) {
        const int kr = kg * 32 + q5;
#pragma unroll
        for (int c = 0; c < 4; ++c) {
          bf16x8 kf = *(const bf16x8*)&sm.kv.K[cur][kr][((c * 2 + hi) ^ (kr & 7)) * 8];
          sc[kg] = __builtin_amdgcn_mfma_f32_32x32x16_bf16(kf, qreg[c], sc[kg], 0, 0, 0);
        }
      }
      __builtin_amdgcn_s_setprio(0);

      if (jt * 64 + 63 > qbase_w) {
        const int kb = jt * 64;
#pragma unroll
        for (int r = 0; r < 16; ++r) {
          const int kl = kb + (r & 3) + 8 * (r >> 2) + 4 * hi;
          if (kl > qg)      sc[0][r] = -1e30f;
          if (kl + 32 > qg) sc[1][r] = -1e30f;
        }
      }

      float pmax = fmaxf(tmax16(sc[0]), tmax16(sc[1]));
      pmax = fmaxf(pmax, __shfl_xor(pmax, 32, 64));
      if (!__all(pmax - mrun <= 8.0f)) {
        const float mnew = fmaxf(mrun, pmax);
        const float alpha = __builtin_amdgcn_exp2f(mrun - mnew);
        mrun = mnew;
        lsum *= alpha;
#pragma unroll
        for (int r = 0; r < 16; ++r) { oacc[0][r] *= alpha; oacc[1][r] *= alpha; }
      }
#pragma unroll
      for (int kg = 0; kg < 2; ++kg)
#pragma unroll
        for (int r = 0; r < 16; ++r)
          sc[kg][r] = __builtin_amdgcn_exp2f(sc[kg][r] - mrun);
      float rsum = tsum16(sc[0]) + tsum16(sc[1]);
      rsum += __shfl_xor(rsum, 32, 64);
      lsum += rsum;

      bf16x8 pf[4];
#pragma unroll
      for (int kc = 0; kc < 4; ++kc) {
        const int kg = kc >> 1, rA = (kc & 1) * 8, rB = rA + 4;
        uint32_t A0, A1, B0, B1;
        asm("v_cvt_pk_bf16_f32 %0, %1, %2" : "=v"(A0) : "v"(sc[kg][rA + 0]), "v"(sc[kg][rA + 1]));
        asm("v_cvt_pk_bf16_f32 %0, %1, %2" : "=v"(A1) : "v"(sc[kg][rA + 2]), "v"(sc[kg][rA + 3]));
        asm("v_cvt_pk_bf16_f32 %0, %1, %2" : "=v"(B0) : "v"(sc[kg][rB + 0]), "v"(sc[kg][rB + 1]));
        asm("v_cvt_pk_bf16_f32 %0, %1, %2" : "=v"(B1) : "v"(sc[kg][rB + 2]), "v"(sc[kg][rB + 3]));
        asm("v_permlane32_swap_b32 %0, %1" : "+v"(A0), "+v"(B0));
        asm("v_permlane32_swap_b32 %0, %1" : "+v"(A1), "+v"(B1));
        union { uint32_t u[4]; bf16x8 v; } cv;
        cv.u[0] = A0; cv.u[1] = A1; cv.u[2] = B0; cv.u[3] = B1;
        pf[kc] = cv.v;
      }

      __builtin_amdgcn_s_setprio(1);
#pragma unroll
      for (int dg = 0; dg < 2; ++dg) {
        const int vr = dg * 32 + q5;
#pragma unroll
        for (int kc = 0; kc < 4; ++kc) {
          bf16x8 vf = *(const bf16x8*)&sm.kv.V[cur][vr][((kc * 2 + hi) ^ (vr & 7)) * 8];
          oacc[dg] = __builtin_amdgcn_mfma_f32_32x32x16_bf16(vf, pf[kc], oacc[dg], 0, 0, 0);
        }
      }
      __builtin_amdgcn_s_setprio(0);
    }

    __syncthreads();
    cur ^= 1;
  }

  if (hi == 0)
    ml[(size_t)(half * 32 + bh) * S_LEN + qg] = make_float2(mrun, lsum);

  const float inv = (lsum > 0.0f) ? (1.0f / lsum) : 0.0f;
#pragma unroll
  for (int dg = 0; dg < 2; ++dg)
#pragma unroll
    for (int g = 0; g < 4; ++g) {
      ushort4 ok;
      ok.x = f2bf(oacc[dg][4 * g + 0] * inv); ok.y = f2bf(oacc[dg][4 * g + 1] * inv);
      ok.z = f2bf(oacc[dg][4 * g + 2] * inv); ok.w = f2bf(oacc[dg][4 * g + 3] * inv);
      *(ushort4*)&sm.Ot[w * 32 + q5][dg * 32 + g * 8 + 4 * hi] = ok;
    }
  __syncthreads();
  {
    const int row = t >> 1, c32 = (t & 1) * 32;
    const size_t gb = ((size_t)(half * 32 + bh) * S_LEN + qt * 128 + row) * 64 + c32;
#pragma unroll
    for (int j = 0; j < 4; ++j)
      *(uint4*)&op[gb + j * 8] = *(const uint4*)&sm.Ot[row][c32 + j * 8];
  }
}

// ---------------- combine the two split-KV halves ----------------
__global__ void attn_combine(const ushort* __restrict__ op, const float2* __restrict__ ml,
                             ushort* __restrict__ Ob) {
  const int idx = blockIdx.x * 256 + threadIdx.x;
  const int d8 = (idx & 7) * 8;
  const int row = idx >> 3;
  const int bh = row >> 11, q = row & 2047;
  const int b = bh >> 4, h = bh & 15;

  const float2 m1 = ml[row];
  const float2 m2 = ml[65536 + row];
  const float m = fmaxf(m1.x, m2.x);
  const float w1 = m1.y * __builtin_amdgcn_exp2f(m1.x - m);
  const float w2 = m2.y * __builtin_amdgcn_exp2f(m2.x - m);
  const float s = 1.0f / (w1 + w2);
  const float s1 = w1 * s, s2 = w2 * s;

  uint4 a = *(const uint4*)&op[(size_t)row * 64 + d8];
  uint4 c = *(const uint4*)&op[(size_t)(65536 + row) * 64 + d8];
  const uint32_t* aw = (const uint32_t*)&a;
  const uint32_t* cw = (const uint32_t*)&c;
  uint32_t o[4];
#pragma unroll
  for (int j = 0; j < 4; ++j) {
    float lo = s1 * bf2f((ushort)(aw[j] & 0xffff)) + s2 * bf2f((ushort)(cw[j] & 0xffff));
    float hi = s1 * bf2f((ushort)(aw[j] >> 16))    + s2 * bf2f((ushort)(cw[j] >> 16));
    o[j] = (uint32_t)f2bf(lo) | ((uint32_t)f2bf(hi) << 16);
  }
  *(uint4*)&Ob[((size_t)(b * S_LEN + q)) * DM + h * 64 + d8] = *(const uint4*)o;
}

extern "C" void kernel_launch(void* const* d_in, const int* in_sizes, int n_in,
                              void* d_out, int out_size, void* d_ws, size_t ws_size,
                              hipStream_t stream) {
  const float* x     = (const float*)d_in[0];
  const float* w_qkv = (const float*)d_in[2];
  const float* w_out = (const float*)d_in[3];
  float* out = (float*)d_out;

  char* ws = (char*)d_ws;
  ushort* xb    = (ushort*)(ws);
  ushort* wqkvb = (ushort*)(ws + 8388608);
  ushort* woutb = (ushort*)(ws + 14680064);
  ushort* Qh    = (ushort*)(ws + 41943040);
  ushort* Kh    = (ushort*)(ws + 50331648);
  ushort* Vt    = (ushort*)(ws + 58720256);
  ushort* Ob    = (ushort*)(ws + 67108864);
  float2* tab   = (float2*)(ws + 75497472);
  ushort* op    = (ushort*)(ws + 16777216);   // 16 MB: (2,32,2048,64) bf16
  float2* ml    = (float2*)(ws + 33554432);   //  1 MB: (2,32,2048) float2

  prep<<<2048, 256, 0, stream>>>(x, w_qkv, w_out, xb, wqkvb, woutb, tab);

  // fused: qkv GEMM + rope(Q,K) + transpose(V)
  gemm_qkv<<<dim3(24, 32), 256, 0, stream>>>(xb, wqkvb, tab, Qh, Kh, Vt);

  flash_attn6<<<dim3(32, 16, 2), 256, 0, stream>>>(Qh, Kh, Vt, op, ml);
  attn_combine<<<2048, 256, 0, stream>>>(op, ml, Ob);

  gemm_bt4<0><<<dim3(8, 32), 256, 0, stream>>>(Ob, woutb, out, 4096, 1024, 1024);
}